// Round 7
// baseline (373.672 us; speedup 1.0000x reference)
//
#include <hip/hip_runtime.h>

// SimpleHashEncoder1D: out[n, l*2+f] = hash_table[floor(xn*scale[l]+0.5) & (T-1)][f]
// xn = (x+bound)/(2*bound), scale[l] = 16*b^l - 1
//
// float32 bit-exactness (verified R1..R9, absmax == 0.0):
//   bits(scale[l]) = ((130+l)<<23) | (0x800000 - (0x100000>>l) - l)
//   separate mul/add (no contraction), __fdiv_rn normalize, trunc==floor,
//   '&(T-1)' == '%T' since idx < 2^19.
//
// Ledger: R4 338 best; R5 stores-flavor neutral; R6 sc0-all +32; R7 selective
// sc0 neutral; R8 LDS levels 0-10 neutral; R9 bin-then-encode neutral (ws
// path unverifiable + per-block window refetch). Surviving composite model:
// time ~ max(fine-level random 128B LINE-FILL traffic, store-stream term).
//
// R10: FUSED FINE-LEVEL RECORDS. u = idx15 pins xn to a 1/s15 window, so
// idx_l (l=11..14) takes at most 2 values and idx15 == u. k_build makes a
// 128 B record per u: {A,B entry pairs + base idx for l=11..14, unique l=15
// entry}. Main kernel = R4 n-order/sequential-store structure, but lanes
// j>=5 fetch ONE random 128 B line (the record) instead of 5 random 8 B
// probes over 4 MB: fine-line traffic 1.34 GB -> 268 MB. Level 10 direct
// (128 KB window, L2-hit). Selection compares exact idx_l vs stored base,
// with guarded direct-gather fallback -> absmax 0 structural.
// No silent fallback: ws_size >= 64 MB uses ws; else records live in the
// TAIL of out, main covers first 7/8 slots, direct kernel finishes tail.

constexpr int T_SIZE = 524288;   // 2^19
constexpr int N_PTS  = 2097152;  // 2^21
constexpr int SLOTS  = N_PTS * 8;       // 2^24 float4 output slots
constexpr int KI     = 4;               // slots per thread
constexpr unsigned REC_N = 524288;      // one record per u = idx15
constexpr size_t REC_BYTES = (size_t)REC_N * 128;   // 64 MiB

typedef float vfloat4 __attribute__((ext_vector_type(4)));

__device__ __forceinline__ float scale_for_level(int l) {
    unsigned bits = ((130u + (unsigned)l) << 23)
                  | (0x800000u - (0x100000u >> l) - (unsigned)l);
    return __uint_as_float(bits);
}

// two-ulp-down: safety margin so iA is a true lower bound of idx_l over the
// u-window; any residual off-by-one is caught by the select's guard path.
__device__ __forceinline__ float prev2(float f) {
    if (!(f > 0.0f)) return 0.0f;
    return __uint_as_float(__float_as_uint(f) - 2u);
}

// ---------------- k_build: one 128 B record per u ----------------
// Record layout (bytes):
//   0: e11A,e11B  16: e12A,e12B  32: e13A,e13B  48: e14A,e14B  (float2 pairs)
//  64: e15 (float2, unique since idx15==u)
//  72: iA11  76: iA12  80: iA13  84: iA14   88..127: pad
__global__ __launch_bounds__(256) void k_build(
    const float* __restrict__ table, float* __restrict__ rec)
{
    __shared__ float smem[256 * 32];     // 256 records x 128 B staging
    int t = threadIdx.x;
    unsigned u = blockIdx.x * 256u + (unsigned)t;

    float s15  = scale_for_level(15);
    float xnlo = prev2(__fdiv_rn((float)u - 0.5f, s15));  // window lower edge

    float* r = &smem[t * 32];
    const float2* t2 = (const float2*)table;
#pragma unroll
    for (int l = 11; l <= 14; ++l) {
        float sl = scale_for_level(l);
        int iA = (int)__fadd_rn(__fmul_rn(xnlo, sl), 0.5f);   // >= 0
        int iB = iA + 1; if (iB > T_SIZE - 1) iB = T_SIZE - 1;
        float2 eA = t2[iA], eB = t2[iB];
        int k = l - 11;
        r[k * 4 + 0] = eA.x; r[k * 4 + 1] = eA.y;
        r[k * 4 + 2] = eB.x; r[k * 4 + 3] = eB.y;
        ((int*)r)[18 + k] = iA;          // words 18..21 = bytes 72..87
    }
    float2 e15 = t2[u];
    r[16] = e15.x; r[17] = e15.y;
#pragma unroll
    for (int w = 22; w < 32; ++w) r[w] = 0.0f;   // pad
    __syncthreads();

    // coalesced copy: 2048 float4 per block, plain stores (keep hot in L2/L3)
    vfloat4* dst = (vfloat4*)rec + (size_t)blockIdx.x * 2048;
    const vfloat4* src = (const vfloat4*)smem;
#pragma unroll
    for (int m = 0; m < 8; ++m) dst[t + m * 256] = src[t + m * 256];
}

// ---------------- k_main: R4 structure + record-served fine levels ----------------
__global__ __launch_bounds__(256) void k_main(
    const float* __restrict__ x,
    const float* __restrict__ table,
    const int* __restrict__ bound_p,
    float* __restrict__ out,
    const float* __restrict__ rec,
    int base, int nth)              // base,nth multiples of 8 -> j constant
{
    int tid   = blockIdx.x * 256 + threadIdx.x;
    int slot0 = base + tid;
    int j  = slot0 & 7;
    float s0  = scale_for_level(j << 1);
    float s1  = scale_for_level((j << 1) + 1);
    float s15 = scale_for_level(15);
    float fb  = (float)bound_p[0];
    float fb2 = __fmul_rn(2.0f, fb);

    float xn[KI]; int i0[KI], i1[KI];
#pragma unroll
    for (int k = 0; k < KI; ++k) {
        int slot = slot0 + k * nth;
        float xv = __builtin_nontemporal_load(&x[slot >> 3]);
        xn[k] = __fdiv_rn(__fadd_rn(xv, fb), fb2);
        float xs0 = __fadd_rn(__fmul_rn(xn[k], s0), 0.5f);
        float xs1 = __fadd_rn(__fmul_rn(xn[k], s1), 0.5f);
        i0[k] = ((int)xs0) & (T_SIZE - 1);
        i1[k] = ((int)xs1) & (T_SIZE - 1);
    }

    const float2* t2 = (const float2*)table;
    float2 a[KI], b[KI];
    if (j <= 4) {                 // levels 0..9: direct, L1/L2-resident (= R4)
#pragma unroll
        for (int k = 0; k < KI; ++k) { a[k] = t2[i0[k]]; b[k] = t2[i1[k]]; }
    } else if (j == 5) {          // level 10 direct (128 KB window); 11 via record
#pragma unroll
        for (int k = 0; k < KI; ++k) {
            a[k] = t2[i0[k]];
            unsigned u = ((unsigned)(int)__fadd_rn(__fmul_rn(xn[k], s15), 0.5f))
                         & (T_SIZE - 1);
            const char* rb = (const char*)rec + ((size_t)u << 7);
            vfloat4 w = *(const vfloat4*)(rb);
            int iA = *(const int*)(rb + 72);
            int s = i1[k] - iA;
            b[k] = (s == 0) ? make_float2(w.x, w.y)
                 : (s == 1) ? make_float2(w.z, w.w)
                 : t2[i1[k]];                     // guard: never/rare
        }
    } else if (j == 6) {          // levels 12,13 via record
#pragma unroll
        for (int k = 0; k < KI; ++k) {
            unsigned u = ((unsigned)(int)__fadd_rn(__fmul_rn(xn[k], s15), 0.5f))
                         & (T_SIZE - 1);
            const char* rb = (const char*)rec + ((size_t)u << 7);
            vfloat4 w0 = *(const vfloat4*)(rb + 16);
            vfloat4 w1 = *(const vfloat4*)(rb + 32);
            int iA12 = *(const int*)(rb + 76);
            int iA13 = *(const int*)(rb + 80);
            int sA = i0[k] - iA12, sB = i1[k] - iA13;
            a[k] = (sA == 0) ? make_float2(w0.x, w0.y)
                 : (sA == 1) ? make_float2(w0.z, w0.w) : t2[i0[k]];
            b[k] = (sB == 0) ? make_float2(w1.x, w1.y)
                 : (sB == 1) ? make_float2(w1.z, w1.w) : t2[i1[k]];
        }
    } else {                      // j==7: level 14 via record; 15 unique (i1==u)
#pragma unroll
        for (int k = 0; k < KI; ++k) {
            unsigned u = (unsigned)i1[k];         // idx15 IS the record key
            const char* rb = (const char*)rec + ((size_t)u << 7);
            vfloat4 w   = *(const vfloat4*)(rb + 48);
            float2 e15  = *(const float2*)(rb + 64);
            int iA14 = *(const int*)(rb + 84);
            int sA = i0[k] - iA14;
            a[k] = (sA == 0) ? make_float2(w.x, w.y)
                 : (sA == 1) ? make_float2(w.z, w.w) : t2[i0[k]];
            b[k] = e15;
        }
    }

#pragma unroll
    for (int k = 0; k < KI; ++k) {
        vfloat4 o;
        o.x = a[k].x; o.y = a[k].y; o.z = b[k].x; o.w = b[k].y;
        __builtin_nontemporal_store(o, (vfloat4*)out + (slot0 + k * nth));
    }
}

// ---------------- k_direct: R4 body over a slot range (tail finisher) ----------------
__global__ __launch_bounds__(256) void k_direct(
    const float* __restrict__ x,
    const float* __restrict__ table,
    const int* __restrict__ bound_p,
    float* __restrict__ out,
    int base, int nth)
{
    int tid   = blockIdx.x * 256 + threadIdx.x;
    int slot0 = base + tid;
    int j = slot0 & 7;
    float s0 = scale_for_level(j << 1);
    float s1 = scale_for_level((j << 1) + 1);
    float fb  = (float)bound_p[0];
    float fb2 = __fmul_rn(2.0f, fb);

    float xv[KI];
#pragma unroll
    for (int k = 0; k < KI; ++k)
        xv[k] = __builtin_nontemporal_load(&x[(slot0 + k * nth) >> 3]);

    int i0[KI], i1[KI];
#pragma unroll
    for (int k = 0; k < KI; ++k) {
        float xn  = __fdiv_rn(__fadd_rn(xv[k], fb), fb2);
        float xs0 = __fadd_rn(__fmul_rn(xn, s0), 0.5f);
        float xs1 = __fadd_rn(__fmul_rn(xn, s1), 0.5f);
        i0[k] = ((int)xs0) & (T_SIZE - 1);
        i1[k] = ((int)xs1) & (T_SIZE - 1);
    }

    const float2* t2 = (const float2*)table;
    float2 a[KI], b[KI];
#pragma unroll
    for (int k = 0; k < KI; ++k) { a[k] = t2[i0[k]]; b[k] = t2[i1[k]]; }

#pragma unroll
    for (int k = 0; k < KI; ++k) {
        vfloat4 o;
        o.x = a[k].x; o.y = a[k].y; o.z = b[k].x; o.w = b[k].y;
        __builtin_nontemporal_store(o, (vfloat4*)out + (slot0 + k * nth));
    }
}

extern "C" void kernel_launch(void* const* d_in, const int* in_sizes, int n_in,
                              void* d_out, int out_size, void* d_ws, size_t ws_size,
                              hipStream_t stream) {
    const float* x     = (const float*)d_in[0];
    const float* table = (const float*)d_in[1];
    const int*   bound = (const int*)d_in[2];
    float* out = (float*)d_out;

    if (d_ws != nullptr && ws_size >= REC_BYTES) {
        // records in workspace; main kernel covers ALL slots (R4 grid)
        float* rec = (float*)d_ws;
        k_build<<<REC_N / 256, 256, 0, stream>>>(table, rec);
        int nth = SLOTS / KI;                       // 4194304, %8==0
        k_main<<<nth / 256, 256, 0, stream>>>(x, table, bound, out, rec, 0, nth);
    } else {
        // records in the TAIL of out (last 2^22 slots = 64 MiB);
        // main covers first 7/8 of slots via records, then the direct
        // kernel finishes (and overwrites) the tail region.
        constexpr int TAIL_SLOTS = 1 << 22;
        float* rec = out + (size_t)(SLOTS - TAIL_SLOTS) * 4;
        k_build<<<REC_N / 256, 256, 0, stream>>>(table, rec);
        int mainslots = SLOTS - TAIL_SLOTS;         // 12582912
        int nth_m = mainslots / KI;                 // 3145728, %8==0
        k_main<<<nth_m / 256, 256, 0, stream>>>(x, table, bound, out, rec, 0, nth_m);
        int nth_t = TAIL_SLOTS / KI;                // 1048576, %8==0
        k_direct<<<nth_t / 256, 256, 0, stream>>>(x, table, bound, out,
                                                  SLOTS - TAIL_SLOTS, nth_t);
    }
}